// Round 5
// baseline (506.033 us; speedup 1.0000x reference)
//
#include <hip/hip_runtime.h>
#include <hip/hip_bf16.h>

typedef __bf16 bf16x8 __attribute__((ext_vector_type(8)));
typedef float  f32x4  __attribute__((ext_vector_type(4)));

#define M_TOT 8192
#define N_TOT 4096
#define K_TOT 4096
#define NCH   32          // 128-k chunks
#define NPH   16          // phases (2 chunks each)
#define NBROW 256         // 16-wide n-block rows
#define CAP   152         // max compacted tiles per n-block row (incl. pads)

// ws layout (bytes)
#define XP_BYTES   ((size_t)M_TOT * K_TOT * 2)            // 67,108,864
#define WT_BYTES   ((size_t)NBROW * CAP * 512)            // 19,922,944
#define META_BYTES ((size_t)NBROW * CAP)                  // 38,912
#define SEG_BYTES  ((size_t)NBROW * NCH * 4)              // 32,768
#define SLOT_BYTES ((size_t)NBROW * CAP * 2)              // 77,824
#define TOT_BYTES  ((size_t)NBROW * 4)                    // 1,024
#define WS_NEED    (XP_BYTES + WT_BYTES + META_BYTES + SEG_BYTES + SLOT_BYTES + TOT_BYTES)

__device__ int g_flags;

__device__ __forceinline__ void gload_lds16(const void* g, void* l) {
    __builtin_amdgcn_global_load_lds(
        (const __attribute__((address_space(1))) unsigned int*)g,
        (__attribute__((address_space(3))) unsigned int*)l, 16, 0, 0);
}

// ---------------------------------------------------------------------------
// Detect mask storage width; same byte semantics as the scalar version that
// passed, but uint4-vectorized (16 loads/thread instead of 256).
//   word byte1 (i%4==1): ==1 -> width1 bit; in {0x3F,0x80,0x3C} -> width2 bit
//   word byte3 (i%4==3, odd): ==1 -> width1 bit
// ---------------------------------------------------------------------------
__global__ void bsl_detect(const unsigned char* __restrict__ mask) {
    __shared__ int sf[256];
    const int t = threadIdx.x;
    const uint4* mp = (const uint4*)mask + t * 16;
    int f = 0;
    #pragma unroll
    for (int v = 0; v < 16; ++v) {
        const uint4 u = mp[v];
        const unsigned int ws[4] = {u.x, u.y, u.z, u.w};
        #pragma unroll
        for (int wdi = 0; wdi < 4; ++wdi) {
            const unsigned int wv = ws[wdi];
            const unsigned int b1 = (wv >> 8) & 0xffu;
            const unsigned int b3 = (wv >> 24) & 0xffu;
            if (b1 == 1u || b3 == 1u) f |= 1;
            if (b1 == 0x3Fu || b1 == 0x80u || b1 == 0x3Cu) f |= 2;
        }
    }
    sf[t] = f;
    __syncthreads();
    if (t == 0) {
        int acc = 0;
        for (int i = 0; i < 256; ++i) acc |= sf[i];
        g_flags = acc;
    }
}

// ---------------------------------------------------------------------------
// prep_x: fp32 -> bf16, PRE-SWIZZLED: within each 128-k chunk, 16B-unit index
// u (0..15) stored at u ^ (row & 7). GEMM stages with LINEAR global_load_lds
// and reads fragments with the same XOR -> conflict-free ds_read_b128.
// (verbatim from R3, verified)
// ---------------------------------------------------------------------------
__global__ __launch_bounds__(256) void prep_x(
        const float* __restrict__ x, __hip_bfloat16* __restrict__ xp) {
    const long long tid    = (long long)blockIdx.x * 256 + threadIdx.x;
    const long long stride = (long long)gridDim.x * 256;
    const long long TOT    = (long long)M_TOT * K_TOT / 8;
    for (long long g = tid; g < TOT; g += stride) {
        const int row = (int)(g >> 9);
        const int gi  = (int)(g & 511);
        const int ch  = gi >> 4;
        const int u   = gi & 15;
        const int up  = u ^ (row & 7);
        const float4 f0 = ((const float4*)(x + g * 8))[0];
        const float4 f1 = ((const float4*)(x + g * 8))[1];
        union { __hip_bfloat16 h[8]; uint4 v; } cv;
        const float ff[8] = {f0.x, f0.y, f0.z, f0.w, f1.x, f1.y, f1.z, f1.w};
        #pragma unroll
        for (int e = 0; e < 8; ++e) cv.h[e] = __float2bfloat16(ff[e]);
        *(uint4*)((char*)xp + (size_t)row * 8192 + ch * 256 + up * 16) = cv.v;
    }
}

// ---------------------------------------------------------------------------
// prep_w_meta: per n-block row, activity ballot -> per-chunk even-padded
// segments (seg32 = off<<16 | len), chunk-local kb meta, and slotmap/total to
// workspace for the parallel fill kernel.
// ---------------------------------------------------------------------------
__global__ __launch_bounds__(256) void prep_w_meta(
        const unsigned char* __restrict__ mask,
        unsigned char* __restrict__ meta, unsigned int* __restrict__ seg32,
        short* __restrict__ slotws, int* __restrict__ totws) {
    __shared__ int cnt[NCH];
    __shared__ unsigned short offl[NCH + 1];
    __shared__ short slotmap[CAP];

    const int j    = blockIdx.x;
    const int t    = threadIdx.x;     // == global k-block 0..255
    const int lane = t & 63;
    const int flags = g_flags;

    unsigned int v;
    {
        const size_t e = (size_t)(j * 16) * K_TOT + (size_t)t * 16;
        if (flags & 1)      v = mask[e];
        else if (flags & 2) v = ((const unsigned short*)mask)[e];
        else                v = ((const unsigned int*)mask)[e];
    }
    const bool act = (v != 0u);
    const unsigned long long bal = __ballot(act);
    const unsigned int cb = (unsigned int)((bal >> ((lane >> 3) * 8)) & 0xffu);
    if ((lane & 7) == 0) cnt[t >> 3] = __popc(cb);
    if (t < CAP) slotmap[t] = -1;
    __syncthreads();

    if (t == 0) {
        int o = 0;
        for (int ch = 0; ch < NCH; ++ch) {
            int pl = cnt[ch] + (cnt[ch] & 1);        // pad to even
            const int avail = CAP - o;
            if (pl > avail) pl = avail & ~1;         // astronomically unlikely
            offl[ch] = (unsigned short)o;
            seg32[j * NCH + ch] = ((unsigned int)o << 16) | (unsigned int)pl;
            o += pl;
        }
        offl[NCH] = (unsigned short)o;
    }
    __syncthreads();

    if (act) {
        const int ch   = t >> 3;
        const int rank = __popc(cb & ((1u << (lane & 7)) - 1u));
        const int slot = offl[ch] + rank;
        if (slot < (int)offl[ch + 1]) slotmap[slot] = (short)t;
    }
    __syncthreads();

    const int total = offl[NCH];
    if (t < CAP) slotws[j * CAP + t] = slotmap[t];
    if (t < total) {
        const int kbg = slotmap[t];
        meta[j * CAP + t] = (kbg < 0) ? 0 : (unsigned char)(kbg & 7);
    }
    if (t == 0) totws[j] = total;
}

// ---------------------------------------------------------------------------
// prep_w_fill: grid (256 rows, 8 slices). Slice z fills slots z, z+8, ...
// One 16x16 tile per wg-iteration: thread t loads w element (n=t>>4, k=t&15),
// stores bf16 tile [n][k] (512 B). Pad slots (-1) become zero tiles.
// ---------------------------------------------------------------------------
__global__ __launch_bounds__(256) void prep_w_fill(
        const float* __restrict__ w, const short* __restrict__ slotws,
        const int* __restrict__ totws, __hip_bfloat16* __restrict__ wt) {
    const int j = blockIdx.x;
    const int z = blockIdx.y;
    const int t = threadIdx.x;
    const int total = totws[j];
    for (int s = z; s < total; s += 8) {
        const int kbg = slotws[j * CAP + s];
        float val = 0.f;
        if (kbg >= 0)
            val = w[(size_t)(j * 16 + (t >> 4)) * K_TOT + (unsigned)kbg * 16 + (t & 15)];
        wt[(size_t)(j * CAP + s) * 256 + t] = __float2bfloat16(val);
    }
}

// ---------------------------------------------------------------------------
// Main GEMM. wg = 32 m-rows x 512 n-cols (32 n-blocks); 4 waves, wave owns 8
// n-blocks; acc[8][2] f32x4 (static). Per phase (2 chunks = 256 k): stage
// x[32][256] bf16 via 4 global_load_lds16/thread into double-buffered LDS
// (prefetch issued BEFORE compute -> the single per-phase barrier drain hides
// under ~2x compute), then per owned n-block only REAL active pairs:
//   seg from LDS (preloaded once) -> 1 coalesced 1KB W-pair load + u16 meta
//   + 2 swizzled ds_read_b128 + 2 mfma_16x16x32_bf16.
// x raw L3 traffic = 8 x 67 MB = 536 MB (half of R3). LDS 36.9 KB -> 4 wgs/CU.
// Grid (8, 256): wgid%8 == jg == XCD; W slice 2.4 MB L2-resident per XCD.
// ---------------------------------------------------------------------------
__global__ __launch_bounds__(256, 4) void bsl_gemm_ws(
        const __hip_bfloat16* __restrict__ xp,
        const __hip_bfloat16* __restrict__ wt,
        const unsigned char*  __restrict__ meta,
        const unsigned int*   __restrict__ seg32,
        const float* __restrict__ bias,
        float* __restrict__ out) {
    __shared__ __align__(16) __hip_bfloat16 xs[2][32][256];   // 2 x 16 KB; row = 512 B
    __shared__ __align__(16) unsigned int   segL[32 * NCH];   // 4 KB

    const int jg   = blockIdx.x;          // n-group (512 cols)
    const int m0   = blockIdx.y * 32;
    const int t    = threadIdx.x;
    const int wq   = t >> 6;
    const int lane = t & 63;
    const int q    = lane >> 4;
    const int rl   = lane & 15;
    const int r7   = rl & 7;

    // preload all seg words for this wg (32 rows x 32 chunks = 4 KB)
    ((uint4*)segL)[t] = ((const uint4*)(seg32 + jg * 32 * NCH))[t];

    char* const xsb = (char*)&xs[0][0][0];
    // per-lane staging source (xp pre-swizzled -> linear read here)
    const char* xsrc = (const char*)xp
        + (size_t)(m0 + wq * 8 + (lane >> 5)) * 8192 + (lane & 31) * 16;

    auto stage = [&](int b, int ph) {
        char* d0 = xsb + b * 16384 + wq * 4096;
        const char* s0 = xsrc + (size_t)ph * 512;
        #pragma unroll
        for (int i = 0; i < 4; ++i)           // issue i covers rows +2i, +2i+1
            gload_lds16(s0 + (size_t)i * 16384, d0 + i * 1024);
    };

    const int laneoff_w = (q >> 1) * 512 + rl * 32 + (q & 1) * 16;

    f32x4 acc[8][2];
    #pragma unroll
    for (int i = 0; i < 8; ++i) {
        acc[i][0] = (f32x4){0.f, 0.f, 0.f, 0.f};
        acc[i][1] = (f32x4){0.f, 0.f, 0.f, 0.f};
    }

    stage(0, 0);
    __syncthreads();    // segL + first buffer ready

    int buf = 0;
    for (int ph = 0; ph < NPH; ++ph) {
        if (ph + 1 < NPH) stage(buf ^ 1, ph + 1);
        const char* xcur = xsb + buf * 16384;
        #pragma unroll
        for (int cc = 0; cc < 2; ++cc) {
            const int ch = ph * 2 + cc;
            #pragma unroll
            for (int i = 0; i < 8; ++i) {
                const int jl = wq * 8 + i;
                const unsigned int sg = segL[jl * NCH + ch];
                const int np = (int)(sg & 0xffffu) >> 1;
                const unsigned int off = sg >> 16;
                const int j = jg * 32 + jl;
                const char* wbase = (const char*)wt + (size_t)(j * CAP + off) * 512;
                const unsigned char* mbase = meta + (size_t)j * CAP + off;
                for (int p = 0; p < np; ++p) {
                    const unsigned short mm = *(const unsigned short*)(mbase + 2 * p);
                    bf16x8 b = *(const bf16x8*)(wbase + (size_t)p * 1024 + laneoff_w);
                    const int kbs = (q < 2) ? (mm & 7) : ((mm >> 8) & 7);
                    const int u   = ((kbs * 2 + (q & 1)) ^ r7) * 16;
                    bf16x8 a0 = *(const bf16x8*)(xcur + rl * 512 + cc * 256 + u);
                    acc[i][0] = __builtin_amdgcn_mfma_f32_16x16x32_bf16(a0, b, acc[i][0], 0, 0, 0);
                    bf16x8 a1 = *(const bf16x8*)(xcur + (16 + rl) * 512 + cc * 256 + u);
                    acc[i][1] = __builtin_amdgcn_mfma_f32_16x16x32_bf16(a1, b, acc[i][1], 0, 0, 0);
                }
            }
        }
        __syncthreads();
        buf ^= 1;
    }

    // epilogue: C/D layout col=lane&15, row=q*4+reg
    #pragma unroll
    for (int i = 0; i < 8; ++i) {
        const int col = (jg * 32 + wq * 8 + i) * 16 + rl;
        const float bv = bias[col];
        #pragma unroll
        for (int s = 0; s < 2; ++s)
            #pragma unroll
            for (int rg = 0; rg < 4; ++rg)
                out[(size_t)(m0 + s * 16 + q * 4 + rg) * N_TOT + col] = acc[i][s][rg] + bv;
    }
}

// ---------------------------------------------------------------------------
// Fallback (ws too small): verbatim round-0 kernel, measured 730 us.
// ---------------------------------------------------------------------------
#define FBM 128
__global__ __launch_bounds__(256) void bsl_gemm_fb(
        const float* __restrict__ x,
        const float* __restrict__ w,
        const float* __restrict__ bias,
        const unsigned char* __restrict__ mask,
        float* __restrict__ out) {
    __shared__ __hip_bfloat16 xs[FBM][40];
    __shared__ __hip_bfloat16 wls[16][40];
    __shared__ unsigned long long sball[4];
    __shared__ unsigned char klist[256];

    const int j    = blockIdx.x;
    const int m0   = blockIdx.y * FBM;
    const int t    = threadIdx.x;
    const int wave = t >> 6;
    const int lane = t & 63;
    const int q    = lane >> 4;
    const int rl   = lane & 15;

    const int flags = g_flags;
    unsigned int v;
    {
        const long long e = (long long)(j * 16) * K_TOT + (long long)t * 16;
        if (flags & 1)      v = mask[e];
        else if (flags & 2) v = ((const unsigned short*)mask)[e];
        else                v = ((const unsigned int*)mask)[e];
    }
    const bool active = (v != 0);
    const unsigned long long bal = __ballot(active);
    if (lane == 0) sball[wave] = bal;
    __syncthreads();
    int count = 0;
    #pragma unroll
    for (int wv = 0; wv < 4; ++wv) count += __popcll(sball[wv]);
    if (active) {
        int pos = __popcll(bal & ((1ull << lane) - 1));
        for (int wv = 0; wv < wave; ++wv) pos += __popcll(sball[wv]);
        klist[pos] = (unsigned char)t;
    }
    __syncthreads();

    const int r  = t >> 1;
    const int hh = t & 1;

    f32x4 acc0 = {0.f, 0.f, 0.f, 0.f};
    f32x4 acc1 = {0.f, 0.f, 0.f, 0.f};

    const int npairs = (count + 1) >> 1;
    for (int p = 0; p < npairs; ++p) {
        const int  kb1  = klist[2 * p];
        const bool has2 = (2 * p + 1) < count;
        const int  kb2  = has2 ? (int)klist[2 * p + 1] : kb1;
        const int  kb   = hh ? kb2 : kb1;
        {
            const float4* src = (const float4*)(x + (long long)(m0 + r) * K_TOT + kb * 16);
            float4 f0 = src[0], f1 = src[1], f2 = src[2], f3 = src[3];
            union { __hip_bfloat16 h[16]; uint4 u[2]; } cv;
            const float ff[16] = {f0.x, f0.y, f0.z, f0.w, f1.x, f1.y, f1.z, f1.w,
                                  f2.x, f2.y, f2.z, f2.w, f3.x, f3.y, f3.z, f3.w};
            #pragma unroll
            for (int e = 0; e < 16; ++e) cv.h[e] = __float2bfloat16(ff[e]);
            *(uint4*)(&xs[r][hh * 16])     = cv.u[0];
            *(uint4*)(&xs[r][hh * 16 + 8]) = cv.u[1];
        }
        if (t < 32) {
            const int rw = t >> 1;
            const bool valid = (hh == 0) || has2;
            float4 f0 = {0,0,0,0}, f1 = {0,0,0,0}, f2 = {0,0,0,0}, f3 = {0,0,0,0};
            if (valid) {
                const float4* wsrc = (const float4*)(w + (long long)(j * 16 + rw) * K_TOT + kb * 16);
                f0 = wsrc[0]; f1 = wsrc[1]; f2 = wsrc[2]; f3 = wsrc[3];
            }
            union { __hip_bfloat16 h[16]; uint4 u[2]; } cv;
            const float ff[16] = {f0.x, f0.y, f0.z, f0.w, f1.x, f1.y, f1.z, f1.w,
                                  f2.x, f2.y, f2.z, f2.w, f3.x, f3.y, f3.z, f3.w};
            #pragma unroll
            for (int e = 0; e < 16; ++e) cv.h[e] = __float2bfloat16(ff[e]);
            *(uint4*)(&wls[rw][hh * 16])     = cv.u[0];
            *(uint4*)(&wls[rw][hh * 16 + 8]) = cv.u[1];
        }
        __syncthreads();

        bf16x8 bf = *(const bf16x8*)(&wls[rl][q * 8]);
        bf16x8 a0 = *(const bf16x8*)(&xs[wave * 32 + rl][q * 8]);
        bf16x8 a1 = *(const bf16x8*)(&xs[wave * 32 + 16 + rl][q * 8]);
        acc0 = __builtin_amdgcn_mfma_f32_16x16x32_bf16(a0, bf, acc0, 0, 0, 0);
        acc1 = __builtin_amdgcn_mfma_f32_16x16x32_bf16(a1, bf, acc1, 0, 0, 0);
        __syncthreads();
    }

    const float bv = bias[j * 16 + rl];
    #pragma unroll
    for (int i2 = 0; i2 < 2; ++i2) {
        f32x4 a = i2 ? acc1 : acc0;
        const int base_m = m0 + wave * 32 + i2 * 16 + q * 4;
        #pragma unroll
        for (int rg = 0; rg < 4; ++rg) {
            out[(long long)(base_m + rg) * N_TOT + j * 16 + rl] = a[rg] + bv;
        }
    }
}

extern "C" void kernel_launch(void* const* d_in, const int* in_sizes, int n_in,
                              void* d_out, int out_size, void* d_ws, size_t ws_size,
                              hipStream_t stream) {
    const float* x    = (const float*)d_in[0];
    const float* w    = (const float*)d_in[1];
    const float* bias = (const float*)d_in[2];
    const unsigned char* mask = (const unsigned char*)d_in[3];
    float* out = (float*)d_out;

    bsl_detect<<<1, 256, 0, stream>>>(mask);

    if (d_ws != nullptr && ws_size >= WS_NEED) {
        char* wsb = (char*)d_ws;
        __hip_bfloat16* xp   = (__hip_bfloat16*)wsb;
        __hip_bfloat16* wtl  = (__hip_bfloat16*)(wsb + XP_BYTES);
        unsigned char*  meta = (unsigned char*)(wsb + XP_BYTES + WT_BYTES);
        unsigned int*   seg  = (unsigned int*)(wsb + XP_BYTES + WT_BYTES + META_BYTES);
        short*          slot = (short*)(wsb + XP_BYTES + WT_BYTES + META_BYTES + SEG_BYTES);
        int*            tot  = (int*)(wsb + XP_BYTES + WT_BYTES + META_BYTES + SEG_BYTES + SLOT_BYTES);

        prep_x<<<2048, 256, 0, stream>>>(x, xp);
        prep_w_meta<<<NBROW, 256, 0, stream>>>(mask, meta, seg, slot, tot);
        prep_w_fill<<<dim3(NBROW, 8), 256, 0, stream>>>(w, slot, tot, wtl);
        dim3 grid(N_TOT / 512, M_TOT / 32);   // (8, 256): jg == XCD
        bsl_gemm_ws<<<grid, 256, 0, stream>>>(xp, wtl, meta, seg, bias, out);
    } else {
        dim3 grid(256, M_TOT / FBM);          // (256, 64)
        bsl_gemm_fb<<<grid, 256, 0, stream>>>(x, w, bias, mask, out);
    }
}